// Round 6
// baseline (1435.003 us; speedup 1.0000x reference)
//
#include <hip/hip_runtime.h>
#include <math.h>

#define BD 512      // input dim D
#define HH 128      // hidden dim H
#define KSEL 358    // output dim K (top-k)
#define TR 8        // rows per block
#define NT 256      // threads per block

__device__ __forceinline__ int wave_sum64(int v) {
    #pragma unroll
    for (int off = 32; off > 0; off >>= 1) v += __shfl_xor(v, off, 64);
    return v;
}

// XLA:CPU / Eigen pexp-float (classic cephes) bit-emulation. FROZEN — this
// matches the grading reference bit-for-bit (round 5 PASS, absmax 0.0039).
__device__ __forceinline__ float cephes_expf(float x) {
    x = fminf(x, 88.3762626647950f);
    x = fmaxf(x, -88.3762626647949f);
    float m = floorf(fmaf(x, 1.44269504088896341f, 0.5f));
    float r = __fsub_rn(x, __fmul_rn(m, 0.693359375f));
    r = __fsub_rn(r, __fmul_rn(m, -2.12194440e-4f));
    float r2 = __fmul_rn(r, r);
    float p = 1.9875691500E-4f;
    p = fmaf(p, r, 1.3981999507E-3f);
    p = fmaf(p, r, 8.3334519073E-3f);
    p = fmaf(p, r, 4.1665795894E-2f);
    p = fmaf(p, r, 1.6666665459E-1f);
    p = fmaf(p, r, 5.0000001201E-1f);
    float y = __fadd_rn(fmaf(p, r2, r), 1.0f);
    int mi = (int)m;
    y = __int_as_float(__float_as_int(y) + (mi << 23));
    return y;
}

__device__ __forceinline__ float sig_xla(float z) {
    float t = cephes_expf(-z);
    float d = __fadd_rn(1.0f, t);
    return __fdiv_rn(1.0f, d);
}

__global__ __launch_bounds__(NT, 4)
void afs_fused(const float* __restrict__ x,
               const float* __restrict__ W1,  const float* __restrict__ b1,
               const float* __restrict__ W2,  const float* __restrict__ b2,
               const float* __restrict__ W3,  const float* __restrict__ b3,
               const float* __restrict__ Wg1, const float* __restrict__ bg1,
               const float* __restrict__ Wg2, const float* __restrict__ bg2,
               const float* __restrict__ Wr1, const float* __restrict__ br1,
               const float* __restrict__ Wr2, const float* __restrict__ br2,
               float* __restrict__ out)
{
    __shared__ float xs[TR][BD];    // 16 KB; masked in place in phase 4
    __shared__ float g1s[TR][HH];   // 4 KB  (gate hidden)
    __shared__ float h12[TR][HH];   // 4 KB  (h1 -> h2 -> r, reused with barriers)
    __shared__ float cs[TR][BD];    // 16 KB (combined scores)
    // total 40 KB -> 4 blocks/CU

    const int tid = threadIdx.x;
    const long long row0 = (long long)blockIdx.x * TR;

    // ---------- Phase 0: load x tile ----------
    {
        const float4* src = reinterpret_cast<const float4*>(x + row0 * BD);
        float4* dst = reinterpret_cast<float4*>(&xs[0][0]);
        #pragma unroll
        for (int i = 0; i < (TR * BD / 4) / NT; ++i)
            dst[tid + i * NT] = src[tid + i * NT];
    }
    __syncthreads();

    // ---------- Phase 1: h1 = relu(x@W1+b1) -> h12, g1 = relu(x@Wg1+bg1) -> g1s ----
    // thread = (col-quad q, net, 2-row group). Per-output arithmetic identical to
    // round-5 PASS: sequential-k fmaf, __fadd_rn bias, relu.
    {
        const int q   = tid & 31;            // cols 4q..4q+3
        const int net = (tid >> 5) & 1;      // 0: importance, 1: gate
        const int rg  = tid >> 6;            // rows 2rg, 2rg+1
        const float* __restrict__ W  = net ? Wg1 : W1;
        const float* __restrict__ Bp = net ? bg1 : b1;
        float* __restrict__ obuf = net ? &g1s[0][0] : &h12[0][0];
        const int r0 = 2 * rg, r1 = r0 + 1;
        const int c = 4 * q;
        float a00=0.f,a01=0.f,a02=0.f,a03=0.f;
        float a10=0.f,a11=0.f,a12=0.f,a13=0.f;
        #pragma unroll 4
        for (int k = 0; k < BD; ++k) {
            float4 w = *reinterpret_cast<const float4*>(&W[k * HH + c]);
            float x0 = xs[r0][k];
            float x1 = xs[r1][k];
            a00 = fmaf(x0, w.x, a00); a01 = fmaf(x0, w.y, a01);
            a02 = fmaf(x0, w.z, a02); a03 = fmaf(x0, w.w, a03);
            a10 = fmaf(x1, w.x, a10); a11 = fmaf(x1, w.y, a11);
            a12 = fmaf(x1, w.z, a12); a13 = fmaf(x1, w.w, a13);
        }
        float4 bv = *reinterpret_cast<const float4*>(&Bp[c]);
        float v;
        v = __fadd_rn(a00, bv.x); obuf[r0*HH + c+0] = v > 0.f ? v : 0.f;
        v = __fadd_rn(a01, bv.y); obuf[r0*HH + c+1] = v > 0.f ? v : 0.f;
        v = __fadd_rn(a02, bv.z); obuf[r0*HH + c+2] = v > 0.f ? v : 0.f;
        v = __fadd_rn(a03, bv.w); obuf[r0*HH + c+3] = v > 0.f ? v : 0.f;
        v = __fadd_rn(a10, bv.x); obuf[r1*HH + c+0] = v > 0.f ? v : 0.f;
        v = __fadd_rn(a11, bv.y); obuf[r1*HH + c+1] = v > 0.f ? v : 0.f;
        v = __fadd_rn(a12, bv.z); obuf[r1*HH + c+2] = v > 0.f ? v : 0.f;
        v = __fadd_rn(a13, bv.w); obuf[r1*HH + c+3] = v > 0.f ? v : 0.f;
    }
    __syncthreads();

    // ---------- Phase 2: h2 = relu(h1@W2+b2), written back into h12 ----------
    {
        const int p  = tid & 63;             // cols 2p, 2p+1
        const int rg = tid >> 6;             // rows 2rg, 2rg+1
        const int c0 = 2 * p, r0 = 2 * rg, r1 = r0 + 1;
        float a00=0.f,a01=0.f,a10=0.f,a11=0.f;
        #pragma unroll 4
        for (int k = 0; k < HH; ++k) {
            float2 w = *reinterpret_cast<const float2*>(&W2[k * HH + c0]);
            float h0 = h12[r0][k];
            float h1v = h12[r1][k];
            a00 = fmaf(h0, w.x, a00);  a01 = fmaf(h0, w.y, a01);
            a10 = fmaf(h1v, w.x, a10); a11 = fmaf(h1v, w.y, a11);
        }
        __syncthreads();   // all h1 reads complete before overwrite
        float bv0 = b2[c0], bv1 = b2[c0+1];
        float v;
        v = __fadd_rn(a00, bv0); h12[r0][c0]   = v > 0.f ? v : 0.f;
        v = __fadd_rn(a01, bv1); h12[r0][c0+1] = v > 0.f ? v : 0.f;
        v = __fadd_rn(a10, bv0); h12[r1][c0]   = v > 0.f ? v : 0.f;
        v = __fadd_rn(a11, bv1); h12[r1][c0+1] = v > 0.f ? v : 0.f;
    }
    __syncthreads();

    // ---------- Phase 3: cs = sig(h2@W3+b3) * sig(g1@Wg2+bg2) ----------
    // thread = (col-quad of 512, 4-row group); two passes, same thread owns
    // the same (r,c) in both -> no barrier between passes.
    {
        const int q  = tid & 127;            // cols 4q..4q+3
        const int rg = tid >> 7;             // rows 4rg..4rg+3
        const int c  = 4 * q;
        const int rb = 4 * rg;
        float z[4][4];
        #pragma unroll
        for (int rr = 0; rr < 4; ++rr)
            #pragma unroll
            for (int jj = 0; jj < 4; ++jj) z[rr][jj] = 0.f;
        #pragma unroll 2
        for (int k = 0; k < HH; ++k) {
            float4 w = *reinterpret_cast<const float4*>(&W3[k * BD + c]);
            #pragma unroll
            for (int rr = 0; rr < 4; ++rr) {
                float hv = h12[rb + rr][k];
                z[rr][0] = fmaf(hv, w.x, z[rr][0]);
                z[rr][1] = fmaf(hv, w.y, z[rr][1]);
                z[rr][2] = fmaf(hv, w.z, z[rr][2]);
                z[rr][3] = fmaf(hv, w.w, z[rr][3]);
            }
        }
        {
            float4 bi = *reinterpret_cast<const float4*>(&b3[c]);
            #pragma unroll
            for (int rr = 0; rr < 4; ++rr) {
                cs[rb+rr][c+0] = sig_xla(__fadd_rn(z[rr][0], bi.x));
                cs[rb+rr][c+1] = sig_xla(__fadd_rn(z[rr][1], bi.y));
                cs[rb+rr][c+2] = sig_xla(__fadd_rn(z[rr][2], bi.z));
                cs[rb+rr][c+3] = sig_xla(__fadd_rn(z[rr][3], bi.w));
            }
        }
        #pragma unroll
        for (int rr = 0; rr < 4; ++rr)
            #pragma unroll
            for (int jj = 0; jj < 4; ++jj) z[rr][jj] = 0.f;
        #pragma unroll 2
        for (int k = 0; k < HH; ++k) {
            float4 w = *reinterpret_cast<const float4*>(&Wg2[k * BD + c]);
            #pragma unroll
            for (int rr = 0; rr < 4; ++rr) {
                float gv = g1s[rb + rr][k];
                z[rr][0] = fmaf(gv, w.x, z[rr][0]);
                z[rr][1] = fmaf(gv, w.y, z[rr][1]);
                z[rr][2] = fmaf(gv, w.z, z[rr][2]);
                z[rr][3] = fmaf(gv, w.w, z[rr][3]);
            }
        }
        {
            float4 bq = *reinterpret_cast<const float4*>(&bg2[c]);
            #pragma unroll
            for (int rr = 0; rr < 4; ++rr) {
                cs[rb+rr][c+0] = __fmul_rn(cs[rb+rr][c+0], sig_xla(__fadd_rn(z[rr][0], bq.x)));
                cs[rb+rr][c+1] = __fmul_rn(cs[rb+rr][c+1], sig_xla(__fadd_rn(z[rr][1], bq.y)));
                cs[rb+rr][c+2] = __fmul_rn(cs[rb+rr][c+2], sig_xla(__fadd_rn(z[rr][2], bq.z)));
                cs[rb+rr][c+3] = __fmul_rn(cs[rb+rr][c+3], sig_xla(__fadd_rn(z[rr][3], bq.w)));
            }
        }
    }
    __syncthreads();

    // ---------- Phase 4: per-row top-K, exact on fp32 keys (FROZEN) ----------
    {
        const int lane = tid & 63;
        const int wv = tid >> 6;
        for (int rr = 0; rr < 2; ++rr) {
            const int r = wv + rr * 4;
            unsigned u[8];
            #pragma unroll
            for (int j = 0; j < 8; ++j)
                u[j] = __float_as_uint(cs[r][j * 64 + lane]);

            unsigned lo = 0u, hi = 0xffffffffu;
            while (lo < hi) {
                unsigned mid = lo + ((hi - lo) >> 1);
                int cnt = 0;
                #pragma unroll
                for (int j = 0; j < 8; ++j) cnt += (u[j] > mid) ? 1 : 0;
                cnt = wave_sum64(cnt);
                if (cnt < KSEL) hi = mid; else lo = mid + 1;
            }
            const unsigned T = lo;

            int ngt = 0, neq = 0;
            #pragma unroll
            for (int j = 0; j < 8; ++j) {
                ngt += (u[j] > T) ? 1 : 0;
                neq += (u[j] == T) ? 1 : 0;
            }
            ngt = wave_sum64(ngt);
            neq = wave_sum64(neq);
            const int m = KSEL - ngt;

            unsigned selbits = 0;
            #pragma unroll
            for (int j = 0; j < 8; ++j)
                if (u[j] > T) selbits |= (1u << j);

            if (neq == m) {
                #pragma unroll
                for (int j = 0; j < 8; ++j)
                    if (u[j] == T) selbits |= (1u << j);
            } else {
                int cnt8[8];
                #pragma unroll
                for (int j = 0; j < 8; ++j) cnt8[j] = 0;
                for (int jj = 0; jj < BD; ++jj) {
                    unsigned uj = __float_as_uint(cs[r][jj]);
                    if (uj == T) {
                        #pragma unroll
                        for (int j = 0; j < 8; ++j)
                            cnt8[j] += (u[j] == T && jj < (j * 64 + lane)) ? 1 : 0;
                    }
                }
                #pragma unroll
                for (int j = 0; j < 8; ++j)
                    if (u[j] == T && (ngt + cnt8[j]) < KSEL)
                        selbits |= (1u << j);
            }

            #pragma unroll
            for (int j = 0; j < 8; ++j)
                if (!(selbits & (1u << j))) xs[r][j * 64 + lane] = 0.0f;
        }
    }
    __syncthreads();

    // ---------- Phase R1: r = relu(masked@Wr1 + br1), into h12 (h2 dead) ----------
    {
        const int p  = tid & 63;
        const int rg = tid >> 6;
        const int c0 = 2 * p, r0 = 2 * rg, r1 = r0 + 1;
        float a00=0.f,a01=0.f,a10=0.f,a11=0.f;
        #pragma unroll 4
        for (int k = 0; k < BD; ++k) {
            float2 w = *reinterpret_cast<const float2*>(&Wr1[k * HH + c0]);
            float x0 = xs[r0][k];
            float x1 = xs[r1][k];
            a00 = fmaf(x0, w.x, a00); a01 = fmaf(x0, w.y, a01);
            a10 = fmaf(x1, w.x, a10); a11 = fmaf(x1, w.y, a11);
        }
        float bv0 = br1[c0], bv1 = br1[c0+1];
        float v;
        v = a00 + bv0; h12[r0][c0]   = v > 0.f ? v : 0.f;
        v = a01 + bv1; h12[r0][c0+1] = v > 0.f ? v : 0.f;
        v = a10 + bv0; h12[r1][c0]   = v > 0.f ? v : 0.f;
        v = a11 + bv1; h12[r1][c0+1] = v > 0.f ? v : 0.f;
    }
    __syncthreads();

    // ---------- Phase R2: out = r@Wr2 + br2 ----------
    {
        for (int cc = tid; cc < KSEL; cc += NT) {
            float acc[TR];
            #pragma unroll
            for (int r = 0; r < TR; ++r) acc[r] = 0.f;
            for (int k = 0; k < HH; ++k) {
                float w = Wr2[k * KSEL + cc];
                #pragma unroll
                for (int r = 0; r < TR; ++r)
                    acc[r] = fmaf(h12[r][k], w, acc[r]);
            }
            float bb = br2[cc];
            #pragma unroll
            for (int r = 0; r < TR; ++r)
                out[(row0 + r) * KSEL + cc] = acc[r] + bb;
        }
    }
}

extern "C" void kernel_launch(void* const* d_in, const int* in_sizes, int n_in,
                              void* d_out, int out_size, void* d_ws, size_t ws_size,
                              hipStream_t stream) {
    const float* x   = (const float*)d_in[0];
    const float* W1  = (const float*)d_in[1];
    const float* b1  = (const float*)d_in[2];
    const float* W2  = (const float*)d_in[3];
    const float* b2  = (const float*)d_in[4];
    const float* W3  = (const float*)d_in[5];
    const float* b3  = (const float*)d_in[6];
    const float* Wg1 = (const float*)d_in[7];
    const float* bg1 = (const float*)d_in[8];
    const float* Wg2 = (const float*)d_in[9];
    const float* bg2 = (const float*)d_in[10];
    const float* Wr1 = (const float*)d_in[11];
    const float* br1 = (const float*)d_in[12];
    const float* Wr2 = (const float*)d_in[13];
    const float* br2 = (const float*)d_in[14];
    float* out = (float*)d_out;

    const int nrows = in_sizes[0] / BD;          // 65536
    dim3 grid(nrows / TR), block(NT);
    afs_fused<<<grid, block, 0, stream>>>(x, W1, b1, W2, b2, W3, b3,
                                          Wg1, bg1, Wg2, bg2, Wr1, br1, Wr2, br2, out);
}

// Round 7
// 1111.751 us; speedup vs baseline: 1.2908x; 1.2908x over previous
//
#include <hip/hip_runtime.h>
#include <math.h>

#define BD 512      // input dim D
#define HH 128      // hidden dim H
#define KSEL 358    // output dim K (top-k)
#define TR 8        // rows per block
#define NT 256      // threads per block

__device__ __forceinline__ int wave_sum64(int v) {
    #pragma unroll
    for (int off = 32; off > 0; off >>= 1) v += __shfl_xor(v, off, 64);
    return v;
}

// XLA:CPU / Eigen pexp-float (classic cephes) bit-emulation. FROZEN — this
// matches the grading reference bit-for-bit (round 5 PASS, absmax 0.0039,
// zero mask flips). Do not alter any operation or rounding mode here.
__device__ __forceinline__ float cephes_expf(float x) {
    x = fminf(x, 88.3762626647950f);
    x = fmaxf(x, -88.3762626647949f);
    float m = floorf(fmaf(x, 1.44269504088896341f, 0.5f));
    float r = __fsub_rn(x, __fmul_rn(m, 0.693359375f));
    r = __fsub_rn(r, __fmul_rn(m, -2.12194440e-4f));
    float r2 = __fmul_rn(r, r);
    float p = 1.9875691500E-4f;
    p = fmaf(p, r, 1.3981999507E-3f);
    p = fmaf(p, r, 8.3334519073E-3f);
    p = fmaf(p, r, 4.1665795894E-2f);
    p = fmaf(p, r, 1.6666665459E-1f);
    p = fmaf(p, r, 5.0000001201E-1f);
    float y = __fadd_rn(fmaf(p, r2, r), 1.0f);
    int mi = (int)m;
    y = __int_as_float(__float_as_int(y) + (mi << 23));
    return y;
}

__device__ __forceinline__ float sig_xla(float z) {
    float t = cephes_expf(-z);
    float d = __fadd_rn(1.0f, t);
    return __fdiv_rn(1.0f, d);
}

__global__ __launch_bounds__(NT, 4)
void afs_fused(const float* __restrict__ x,
               const float* __restrict__ W1,  const float* __restrict__ b1,
               const float* __restrict__ W2,  const float* __restrict__ b2,
               const float* __restrict__ W3,  const float* __restrict__ b3,
               const float* __restrict__ Wg1, const float* __restrict__ bg1,
               const float* __restrict__ Wg2, const float* __restrict__ bg2,
               const float* __restrict__ Wr1, const float* __restrict__ br1,
               const float* __restrict__ Wr2, const float* __restrict__ br2,
               float* __restrict__ out)
{
    // 40 KB total -> 4 blocks/CU (was 48 KB / 3 blocks in round 5).
    __shared__ float xs[TR][BD];    // 16 KB; masked in place in phase 4
    __shared__ float h1s[TR][HH];   // 4 KB  (h1; reused as r after phase 2)
    __shared__ float g1s[TR][HH];   // 4 KB  (gate hidden)
    __shared__ float cs[TR][BD];    // 16 KB (first 4 KB doubles as h2 until phase 3 writes)

    float* h2f = &cs[0][0];         // h2[r][k] == h2f[r*HH+k], overlaid on cs rows 0-1
    float (*rs)[HH] = h1s;          // r overlaid on h1s (dead after phase 2)

    const int tid = threadIdx.x;
    const long long row0 = (long long)blockIdx.x * TR;

    // ---------- Phase 0: load x tile ----------
    {
        const float4* src = reinterpret_cast<const float4*>(x + row0 * BD);
        float4* dst = reinterpret_cast<float4*>(&xs[0][0]);
        #pragma unroll
        for (int i = 0; i < (TR * BD / 4) / NT; ++i)
            dst[tid + i * NT] = src[tid + i * NT];
    }
    __syncthreads();

    // ---------- Phase 1: h1 = relu(x@W1+b1), g1 = relu(x@Wg1+bg1) ----------
    // Round-5 mapping/loads verbatim (scalar weight loads, compiler scheduling).
    {
        const int c = tid & (HH - 1);
        const int rbase = (tid >> 7) * 4;
        float a1[4] = {0.f, 0.f, 0.f, 0.f};
        float ga[4] = {0.f, 0.f, 0.f, 0.f};
        for (int k = 0; k < BD; ++k) {
            float w1 = W1[k * HH + c];
            float wg = Wg1[k * HH + c];
            #pragma unroll
            for (int r = 0; r < 4; ++r) {
                float xv = xs[rbase + r][k];
                a1[r] = fmaf(xv, w1, a1[r]);
                ga[r] = fmaf(xv, wg, ga[r]);
            }
        }
        float bb1 = b1[c], bbg = bg1[c];
        #pragma unroll
        for (int r = 0; r < 4; ++r) {
            float v1 = __fadd_rn(a1[r], bb1);
            float vg = __fadd_rn(ga[r], bbg);
            h1s[rbase + r][c] = v1 > 0.f ? v1 : 0.f;
            g1s[rbase + r][c] = vg > 0.f ? vg : 0.f;
        }
    }
    __syncthreads();

    // ---------- Phase 2: h2 = relu(h1@W2+b2), into cs-overlay ----------
    {
        const int c = tid & (HH - 1);
        const int rbase = (tid >> 7) * 4;
        float acc[4] = {0.f, 0.f, 0.f, 0.f};
        for (int k = 0; k < HH; ++k) {
            float w = W2[k * HH + c];
            #pragma unroll
            for (int r = 0; r < 4; ++r)
                acc[r] = fmaf(h1s[rbase + r][k], w, acc[r]);
        }
        float bb = b2[c];
        #pragma unroll
        for (int r = 0; r < 4; ++r) {
            float v = __fadd_rn(acc[r], bb);
            h2f[(rbase + r) * HH + c] = v > 0.f ? v : 0.f;
        }
    }
    __syncthreads();

    // ---------- Phase 3: cs = sig(h2@W3+b3) * sig(g1@Wg2+bg2) ----------
    // Both logit accumulations into registers; one barrier (h2 lives in cs);
    // then a single combined write. Per-output op sequence identical to r5:
    // sequential-k fmaf chain, __fadd_rn bias, sig_xla, __fmul_rn product.
    {
        const int c0 = tid, c1 = tid + NT;
        float zi0[TR], zi1[TR], zg0[TR], zg1[TR];
        #pragma unroll
        for (int r = 0; r < TR; ++r) { zi0[r] = 0.f; zi1[r] = 0.f; zg0[r] = 0.f; zg1[r] = 0.f; }
        for (int k = 0; k < HH; ++k) {
            float w0 = W3[k * BD + c0];
            float w1 = W3[k * BD + c1];
            #pragma unroll
            for (int r = 0; r < TR; ++r) {
                float hv = h2f[r * HH + k];
                zi0[r] = fmaf(hv, w0, zi0[r]);
                zi1[r] = fmaf(hv, w1, zi1[r]);
            }
        }
        for (int k = 0; k < HH; ++k) {
            float w0 = Wg2[k * BD + c0];
            float w1 = Wg2[k * BD + c1];
            #pragma unroll
            for (int r = 0; r < TR; ++r) {
                float gv = g1s[r][k];
                zg0[r] = fmaf(gv, w0, zg0[r]);
                zg1[r] = fmaf(gv, w1, zg1[r]);
            }
        }
        __syncthreads();   // all h2 reads complete before cs is overwritten
        float bi0 = b3[c0], bi1 = b3[c1];
        float bq0 = bg2[c0], bq1 = bg2[c1];
        #pragma unroll
        for (int r = 0; r < TR; ++r) {
            cs[r][c0] = __fmul_rn(sig_xla(__fadd_rn(zi0[r], bi0)),
                                  sig_xla(__fadd_rn(zg0[r], bq0)));
            cs[r][c1] = __fmul_rn(sig_xla(__fadd_rn(zi1[r], bi1)),
                                  sig_xla(__fadd_rn(zg1[r], bq1)));
        }
    }
    __syncthreads();

    // ---------- Phase 4: per-row top-K, exact on fp32 keys (FROZEN) ----------
    {
        const int lane = tid & 63;
        const int wv = tid >> 6;
        for (int rr = 0; rr < 2; ++rr) {
            const int r = wv + rr * 4;
            unsigned u[8];
            #pragma unroll
            for (int j = 0; j < 8; ++j)
                u[j] = __float_as_uint(cs[r][j * 64 + lane]);

            unsigned lo = 0u, hi = 0xffffffffu;
            while (lo < hi) {
                unsigned mid = lo + ((hi - lo) >> 1);
                int cnt = 0;
                #pragma unroll
                for (int j = 0; j < 8; ++j) cnt += (u[j] > mid) ? 1 : 0;
                cnt = wave_sum64(cnt);
                if (cnt < KSEL) hi = mid; else lo = mid + 1;
            }
            const unsigned T = lo;

            int ngt = 0, neq = 0;
            #pragma unroll
            for (int j = 0; j < 8; ++j) {
                ngt += (u[j] > T) ? 1 : 0;
                neq += (u[j] == T) ? 1 : 0;
            }
            ngt = wave_sum64(ngt);
            neq = wave_sum64(neq);
            const int m = KSEL - ngt;

            unsigned selbits = 0;
            #pragma unroll
            for (int j = 0; j < 8; ++j)
                if (u[j] > T) selbits |= (1u << j);

            if (neq == m) {
                #pragma unroll
                for (int j = 0; j < 8; ++j)
                    if (u[j] == T) selbits |= (1u << j);
            } else {
                int cnt8[8];
                #pragma unroll
                for (int j = 0; j < 8; ++j) cnt8[j] = 0;
                for (int jj = 0; jj < BD; ++jj) {
                    unsigned uj = __float_as_uint(cs[r][jj]);
                    if (uj == T) {
                        #pragma unroll
                        for (int j = 0; j < 8; ++j)
                            cnt8[j] += (u[j] == T && jj < (j * 64 + lane)) ? 1 : 0;
                    }
                }
                #pragma unroll
                for (int j = 0; j < 8; ++j)
                    if (u[j] == T && (ngt + cnt8[j]) < KSEL)
                        selbits |= (1u << j);
            }

            #pragma unroll
            for (int j = 0; j < 8; ++j)
                if (!(selbits & (1u << j))) xs[r][j * 64 + lane] = 0.0f;
        }
    }
    __syncthreads();

    // ---------- Phase R1: r = relu(masked@Wr1 + br1), into rs(=h1s) ----------
    {
        const int c = tid & (HH - 1);
        const int rbase = (tid >> 7) * 4;
        float acc[4] = {0.f, 0.f, 0.f, 0.f};
        for (int k = 0; k < BD; ++k) {
            float w = Wr1[k * HH + c];
            #pragma unroll
            for (int r = 0; r < 4; ++r)
                acc[r] = fmaf(xs[rbase + r][k], w, acc[r]);
        }
        float bb = br1[c];
        #pragma unroll
        for (int r = 0; r < 4; ++r) {
            float v = acc[r] + bb;
            rs[rbase + r][c] = v > 0.f ? v : 0.f;
        }
    }
    __syncthreads();

    // ---------- Phase R2: out = r@Wr2 + br2 ----------
    {
        for (int cc = tid; cc < KSEL; cc += NT) {
            float acc[TR];
            #pragma unroll
            for (int r = 0; r < TR; ++r) acc[r] = 0.f;
            for (int k = 0; k < HH; ++k) {
                float w = Wr2[k * KSEL + cc];
                #pragma unroll
                for (int r = 0; r < TR; ++r)
                    acc[r] = fmaf(rs[r][k], w, acc[r]);
            }
            float bb = br2[cc];
            #pragma unroll
            for (int r = 0; r < TR; ++r)
                out[(row0 + r) * KSEL + cc] = acc[r] + bb;
        }
    }
}

extern "C" void kernel_launch(void* const* d_in, const int* in_sizes, int n_in,
                              void* d_out, int out_size, void* d_ws, size_t ws_size,
                              hipStream_t stream) {
    const float* x   = (const float*)d_in[0];
    const float* W1  = (const float*)d_in[1];
    const float* b1  = (const float*)d_in[2];
    const float* W2  = (const float*)d_in[3];
    const float* b2  = (const float*)d_in[4];
    const float* W3  = (const float*)d_in[5];
    const float* b3  = (const float*)d_in[6];
    const float* Wg1 = (const float*)d_in[7];
    const float* bg1 = (const float*)d_in[8];
    const float* Wg2 = (const float*)d_in[9];
    const float* bg2 = (const float*)d_in[10];
    const float* Wr1 = (const float*)d_in[11];
    const float* br1 = (const float*)d_in[12];
    const float* Wr2 = (const float*)d_in[13];
    const float* br2 = (const float*)d_in[14];
    float* out = (float*)d_out;

    const int nrows = in_sizes[0] / BD;          // 65536
    dim3 grid(nrows / TR), block(NT);
    afs_fused<<<grid, block, 0, stream>>>(x, W1, b1, W2, b2, W3, b3,
                                          Wg1, bg1, Wg2, bg2, Wr1, br1, Wr2, br2, out);
}

// Round 8
// 1098.518 us; speedup vs baseline: 1.3063x; 1.0120x over previous
//
#include <hip/hip_runtime.h>
#include <math.h>

#define BD 512      // input dim D
#define HH 128      // hidden dim H
#define KSEL 358    // output dim K (top-k)
#define TR 8        // rows per block
#define NT 256      // threads per block

__device__ __forceinline__ int wave_sum64(int v) {
    #pragma unroll
    for (int off = 32; off > 0; off >>= 1) v += __shfl_xor(v, off, 64);
    return v;
}

// XLA:CPU / Eigen pexp-float (classic cephes) bit-emulation. FROZEN — this
// matches the grading reference bit-for-bit (round 5 PASS, absmax 0.0039,
// zero mask flips). Do not alter any operation or rounding mode here.
__device__ __forceinline__ float cephes_expf(float x) {
    x = fminf(x, 88.3762626647950f);
    x = fmaxf(x, -88.3762626647949f);
    float m = floorf(fmaf(x, 1.44269504088896341f, 0.5f));
    float r = __fsub_rn(x, __fmul_rn(m, 0.693359375f));
    r = __fsub_rn(r, __fmul_rn(m, -2.12194440e-4f));
    float r2 = __fmul_rn(r, r);
    float p = 1.9875691500E-4f;
    p = fmaf(p, r, 1.3981999507E-3f);
    p = fmaf(p, r, 8.3334519073E-3f);
    p = fmaf(p, r, 4.1665795894E-2f);
    p = fmaf(p, r, 1.6666665459E-1f);
    p = fmaf(p, r, 5.0000001201E-1f);
    float y = __fadd_rn(fmaf(p, r2, r), 1.0f);
    int mi = (int)m;
    y = __int_as_float(__float_as_int(y) + (mi << 23));
    return y;
}

__device__ __forceinline__ float sig_xla(float z) {
    float t = cephes_expf(-z);
    float d = __fadd_rn(1.0f, t);
    return __fdiv_rn(1.0f, d);
}

__global__ __launch_bounds__(NT, 4)
void afs_fused(const float* __restrict__ x,
               const float* __restrict__ W1,  const float* __restrict__ b1,
               const float* __restrict__ W2,  const float* __restrict__ b2,
               const float* __restrict__ W3,  const float* __restrict__ b3,
               const float* __restrict__ Wg1, const float* __restrict__ bg1,
               const float* __restrict__ Wg2, const float* __restrict__ bg2,
               const float* __restrict__ Wr1, const float* __restrict__ br1,
               const float* __restrict__ Wr2, const float* __restrict__ br2,
               float* __restrict__ out)
{
    // 40 KB total -> 4 blocks/CU.
    __shared__ float xs[TR][BD];    // 16 KB; masked in place in phase 4
    __shared__ float h1s[TR][HH];   // 4 KB  (h1; reused as r after phase 2)
    __shared__ float g1s[TR][HH];   // 4 KB  (gate hidden)
    __shared__ float cs[TR][BD];    // 16 KB (first 4 KB doubles as h2 until phase 3 writes)

    float* h2f = &cs[0][0];         // h2[r][k] == h2f[r*HH+k], overlaid on cs
    float (*rs)[HH] = h1s;          // r overlaid on h1s (dead after phase 2)

    const int tid = threadIdx.x;
    const long long row0 = (long long)blockIdx.x * TR;

    // ---------- Phase 0: load x tile ----------
    {
        const float4* src = reinterpret_cast<const float4*>(x + row0 * BD);
        float4* dst = reinterpret_cast<float4*>(&xs[0][0]);
        #pragma unroll
        for (int i = 0; i < (TR * BD / 4) / NT; ++i)
            dst[tid + i * NT] = src[tid + i * NT];
    }
    __syncthreads();

    // ---------- Phase 1: h1 = relu(x@W1+b1), g1 = relu(x@Wg1+bg1) ----------
    // Same per-output arithmetic as round 5/7 (k-ascending single-acc fmaf).
    // Addressing strength-reduced: one pointer per weight matrix, unroll 8,
    // compile-time imm offsets kk*HH*4 <= 3584 B; one 64-bit incr per 8 k.
    {
        const int c = tid & (HH - 1);
        const int rbase = (tid >> 7) * 4;
        const float* __restrict__ pw1 = W1 + c;
        const float* __restrict__ pwg = Wg1 + c;
        float a1[4] = {0.f, 0.f, 0.f, 0.f};
        float ga[4] = {0.f, 0.f, 0.f, 0.f};
        for (int k0 = 0; k0 < BD; k0 += 8) {
            #pragma unroll
            for (int kk = 0; kk < 8; ++kk) {
                const float w1 = pw1[kk * HH];
                const float wg = pwg[kk * HH];
                #pragma unroll
                for (int r = 0; r < 4; ++r) {
                    const float xv = xs[rbase + r][k0 + kk];
                    a1[r] = fmaf(xv, w1, a1[r]);
                    ga[r] = fmaf(xv, wg, ga[r]);
                }
            }
            pw1 += 8 * HH;
            pwg += 8 * HH;
        }
        float bb1 = b1[c], bbg = bg1[c];
        #pragma unroll
        for (int r = 0; r < 4; ++r) {
            float v1 = __fadd_rn(a1[r], bb1);
            float vg = __fadd_rn(ga[r], bbg);
            h1s[rbase + r][c] = v1 > 0.f ? v1 : 0.f;
            g1s[rbase + r][c] = vg > 0.f ? vg : 0.f;
        }
    }
    __syncthreads();

    // ---------- Phase 2: h2 = relu(h1@W2+b2), into cs-overlay ----------
    {
        const int c = tid & (HH - 1);
        const int rbase = (tid >> 7) * 4;
        const float* __restrict__ pw = W2 + c;
        float acc[4] = {0.f, 0.f, 0.f, 0.f};
        for (int k0 = 0; k0 < HH; k0 += 8) {
            #pragma unroll
            for (int kk = 0; kk < 8; ++kk) {
                const float w = pw[kk * HH];
                #pragma unroll
                for (int r = 0; r < 4; ++r)
                    acc[r] = fmaf(h1s[rbase + r][k0 + kk], w, acc[r]);
            }
            pw += 8 * HH;
        }
        float bb = b2[c];
        #pragma unroll
        for (int r = 0; r < 4; ++r) {
            float v = __fadd_rn(acc[r], bb);
            h2f[(rbase + r) * HH + c] = v > 0.f ? v : 0.f;
        }
    }
    __syncthreads();

    // ---------- Phase 3: cs = sig(h2@W3+b3) * sig(g1@Wg2+bg2) ----------
    // One pointer serves both owned columns (c0, c0+256): imm offsets
    // {0, 1024, 2048, 3072} B with unroll 2; one incr per 2 k.
    {
        const int c0 = tid, c1 = tid + NT;
        float zi0[TR], zi1[TR], zg0[TR], zg1[TR];
        #pragma unroll
        for (int r = 0; r < TR; ++r) { zi0[r] = 0.f; zi1[r] = 0.f; zg0[r] = 0.f; zg1[r] = 0.f; }
        {
            const float* __restrict__ pw = W3 + c0;
            for (int k0 = 0; k0 < HH; k0 += 2) {
                #pragma unroll
                for (int kk = 0; kk < 2; ++kk) {
                    const float w0 = pw[kk * BD];
                    const float w1 = pw[kk * BD + NT];
                    #pragma unroll
                    for (int r = 0; r < TR; ++r) {
                        const float hv = h2f[r * HH + k0 + kk];
                        zi0[r] = fmaf(hv, w0, zi0[r]);
                        zi1[r] = fmaf(hv, w1, zi1[r]);
                    }
                }
                pw += 2 * BD;
            }
        }
        {
            const float* __restrict__ pw = Wg2 + c0;
            for (int k0 = 0; k0 < HH; k0 += 2) {
                #pragma unroll
                for (int kk = 0; kk < 2; ++kk) {
                    const float w0 = pw[kk * BD];
                    const float w1 = pw[kk * BD + NT];
                    #pragma unroll
                    for (int r = 0; r < TR; ++r) {
                        const float gv = g1s[r][k0 + kk];
                        zg0[r] = fmaf(gv, w0, zg0[r]);
                        zg1[r] = fmaf(gv, w1, zg1[r]);
                    }
                }
                pw += 2 * BD;
            }
        }
        __syncthreads();   // all h2 reads complete before cs is overwritten
        float bi0 = b3[c0], bi1 = b3[c1];
        float bq0 = bg2[c0], bq1 = bg2[c1];
        #pragma unroll
        for (int r = 0; r < TR; ++r) {
            cs[r][c0] = __fmul_rn(sig_xla(__fadd_rn(zi0[r], bi0)),
                                  sig_xla(__fadd_rn(zg0[r], bq0)));
            cs[r][c1] = __fmul_rn(sig_xla(__fadd_rn(zi1[r], bi1)),
                                  sig_xla(__fadd_rn(zg1[r], bq1)));
        }
    }
    __syncthreads();

    // ---------- Phase 4: per-row top-K, exact on fp32 keys (FROZEN) ----------
    {
        const int lane = tid & 63;
        const int wv = tid >> 6;
        for (int rr = 0; rr < 2; ++rr) {
            const int r = wv + rr * 4;
            unsigned u[8];
            #pragma unroll
            for (int j = 0; j < 8; ++j)
                u[j] = __float_as_uint(cs[r][j * 64 + lane]);

            unsigned lo = 0u, hi = 0xffffffffu;
            while (lo < hi) {
                unsigned mid = lo + ((hi - lo) >> 1);
                int cnt = 0;
                #pragma unroll
                for (int j = 0; j < 8; ++j) cnt += (u[j] > mid) ? 1 : 0;
                cnt = wave_sum64(cnt);
                if (cnt < KSEL) hi = mid; else lo = mid + 1;
            }
            const unsigned T = lo;

            int ngt = 0, neq = 0;
            #pragma unroll
            for (int j = 0; j < 8; ++j) {
                ngt += (u[j] > T) ? 1 : 0;
                neq += (u[j] == T) ? 1 : 0;
            }
            ngt = wave_sum64(ngt);
            neq = wave_sum64(neq);
            const int m = KSEL - ngt;

            unsigned selbits = 0;
            #pragma unroll
            for (int j = 0; j < 8; ++j)
                if (u[j] > T) selbits |= (1u << j);

            if (neq == m) {
                #pragma unroll
                for (int j = 0; j < 8; ++j)
                    if (u[j] == T) selbits |= (1u << j);
            } else {
                int cnt8[8];
                #pragma unroll
                for (int j = 0; j < 8; ++j) cnt8[j] = 0;
                for (int jj = 0; jj < BD; ++jj) {
                    unsigned uj = __float_as_uint(cs[r][jj]);
                    if (uj == T) {
                        #pragma unroll
                        for (int j = 0; j < 8; ++j)
                            cnt8[j] += (u[j] == T && jj < (j * 64 + lane)) ? 1 : 0;
                    }
                }
                #pragma unroll
                for (int j = 0; j < 8; ++j)
                    if (u[j] == T && (ngt + cnt8[j]) < KSEL)
                        selbits |= (1u << j);
            }

            #pragma unroll
            for (int j = 0; j < 8; ++j)
                if (!(selbits & (1u << j))) xs[r][j * 64 + lane] = 0.0f;
        }
    }
    __syncthreads();

    // ---------- Phase R1: r = relu(masked@Wr1 + br1), into rs(=h1s) ----------
    {
        const int c = tid & (HH - 1);
        const int rbase = (tid >> 7) * 4;
        const float* __restrict__ pw = Wr1 + c;
        float acc[4] = {0.f, 0.f, 0.f, 0.f};
        for (int k0 = 0; k0 < BD; k0 += 8) {
            #pragma unroll
            for (int kk = 0; kk < 8; ++kk) {
                const float w = pw[kk * HH];
                #pragma unroll
                for (int r = 0; r < 4; ++r)
                    acc[r] = fmaf(xs[rbase + r][k0 + kk], w, acc[r]);
            }
            pw += 8 * HH;
        }
        float bb = br1[c];
        #pragma unroll
        for (int r = 0; r < 4; ++r) {
            float v = acc[r] + bb;
            rs[rbase + r][c] = v > 0.f ? v : 0.f;
        }
    }
    __syncthreads();

    // ---------- Phase R2: out = r@Wr2 + br2 ----------
    {
        for (int cc = tid; cc < KSEL; cc += NT) {
            const float* __restrict__ pw = Wr2 + cc;
            float acc[TR];
            #pragma unroll
            for (int r = 0; r < TR; ++r) acc[r] = 0.f;
            for (int k0 = 0; k0 < HH; k0 += 2) {
                #pragma unroll
                for (int kk = 0; kk < 2; ++kk) {
                    const float w = pw[kk * KSEL];
                    #pragma unroll
                    for (int r = 0; r < TR; ++r)
                        acc[r] = fmaf(rs[r][k0 + kk], w, acc[r]);
                }
                pw += 2 * KSEL;
            }
            float bb = br2[cc];
            #pragma unroll
            for (int r = 0; r < TR; ++r)
                out[(row0 + r) * KSEL + cc] = acc[r] + bb;
        }
    }
}

extern "C" void kernel_launch(void* const* d_in, const int* in_sizes, int n_in,
                              void* d_out, int out_size, void* d_ws, size_t ws_size,
                              hipStream_t stream) {
    const float* x   = (const float*)d_in[0];
    const float* W1  = (const float*)d_in[1];
    const float* b1  = (const float*)d_in[2];
    const float* W2  = (const float*)d_in[3];
    const float* b2  = (const float*)d_in[4];
    const float* W3  = (const float*)d_in[5];
    const float* b3  = (const float*)d_in[6];
    const float* Wg1 = (const float*)d_in[7];
    const float* bg1 = (const float*)d_in[8];
    const float* Wg2 = (const float*)d_in[9];
    const float* bg2 = (const float*)d_in[10];
    const float* Wr1 = (const float*)d_in[11];
    const float* br1 = (const float*)d_in[12];
    const float* Wr2 = (const float*)d_in[13];
    const float* br2 = (const float*)d_in[14];
    float* out = (float*)d_out;

    const int nrows = in_sizes[0] / BD;          // 65536
    dim3 grid(nrows / TR), block(NT);
    afs_fused<<<grid, block, 0, stream>>>(x, W1, b1, W2, b2, W3, b3,
                                          Wg1, bg1, Wg2, bg2, Wr1, br1, Wr2, br2, out);
}

// Round 9
// 1089.357 us; speedup vs baseline: 1.3173x; 1.0084x over previous
//
#include <hip/hip_runtime.h>
#include <math.h>

#define BD 512      // input dim D
#define HH 128      // hidden dim H
#define KSEL 358    // output dim K (top-k)
#define TR 8        // rows per block
#define NT 256      // threads per block

__device__ __forceinline__ int wave_sum64(int v) {
    #pragma unroll
    for (int off = 32; off > 0; off >>= 1) v += __shfl_xor(v, off, 64);
    return v;
}

// XLA:CPU / Eigen pexp-float (classic cephes) bit-emulation. FROZEN — this
// matches the grading reference bit-for-bit (round 5 PASS, absmax 0.0039,
// zero mask flips). Do not alter any operation or rounding mode here.
__device__ __forceinline__ float cephes_expf(float x) {
    x = fminf(x, 88.3762626647950f);
    x = fmaxf(x, -88.3762626647949f);
    float m = floorf(fmaf(x, 1.44269504088896341f, 0.5f));
    float r = __fsub_rn(x, __fmul_rn(m, 0.693359375f));
    r = __fsub_rn(r, __fmul_rn(m, -2.12194440e-4f));
    float r2 = __fmul_rn(r, r);
    float p = 1.9875691500E-4f;
    p = fmaf(p, r, 1.3981999507E-3f);
    p = fmaf(p, r, 8.3334519073E-3f);
    p = fmaf(p, r, 4.1665795894E-2f);
    p = fmaf(p, r, 1.6666665459E-1f);
    p = fmaf(p, r, 5.0000001201E-1f);
    float y = __fadd_rn(fmaf(p, r2, r), 1.0f);
    int mi = (int)m;
    y = __int_as_float(__float_as_int(y) + (mi << 23));
    return y;
}

__device__ __forceinline__ float sig_xla(float z) {
    float t = cephes_expf(-z);
    float d = __fadd_rn(1.0f, t);
    return __fdiv_rn(1.0f, d);
}

__global__ __launch_bounds__(NT, 4)
void afs_fused(const float* __restrict__ x,
               const float* __restrict__ W1,  const float* __restrict__ b1,
               const float* __restrict__ W2,  const float* __restrict__ b2,
               const float* __restrict__ W3,  const float* __restrict__ b3,
               const float* __restrict__ Wg1, const float* __restrict__ bg1,
               const float* __restrict__ Wg2, const float* __restrict__ bg2,
               const float* __restrict__ Wr1, const float* __restrict__ br1,
               const float* __restrict__ Wr2, const float* __restrict__ br2,
               float* __restrict__ out)
{
    // 40 KB total -> 4 blocks/CU.
    __shared__ float xs[TR][BD];    // 16 KB; masked in place in phase 4
    __shared__ float h1s[TR][HH];   // 4 KB  (h1; reused as r after phase 2)
    __shared__ float g1s[TR][HH];   // 4 KB  (gate hidden)
    __shared__ float cs[TR][BD];    // 16 KB (first 4 KB doubles as h2 until phase 3 writes)

    float* h2f = &cs[0][0];         // h2[r][k] == h2f[r*HH+k], overlaid on cs
    float (*rs)[HH] = h1s;          // r overlaid on h1s (dead after phase 2)

    const int tid = threadIdx.x;
    const long long row0 = (long long)blockIdx.x * TR;

    // ---------- Phase 0: load x tile ----------
    {
        const float4* src = reinterpret_cast<const float4*>(x + row0 * BD);
        float4* dst = reinterpret_cast<float4*>(&xs[0][0]);
        #pragma unroll
        for (int i = 0; i < (TR * BD / 4) / NT; ++i)
            dst[tid + i * NT] = src[tid + i * NT];
    }
    __syncthreads();

    // ---------- Phase 1: h1 = relu(x@W1+b1), g1 = relu(x@Wg1+bg1) ----------
    // Same per-output arithmetic (k-ascending single-acc fmaf). Activation
    // reads vectorized: 2x ds_read_b128 per row per 8 k (was 8x b32);
    // register quads consumed with static indices (fully unrolled).
    {
        const int c = tid & (HH - 1);
        const int rbase = (tid >> 7) * 4;
        const float* __restrict__ pw1 = W1 + c;
        const float* __restrict__ pwg = Wg1 + c;
        float a1[4] = {0.f, 0.f, 0.f, 0.f};
        float ga[4] = {0.f, 0.f, 0.f, 0.f};
        for (int k0 = 0; k0 < BD; k0 += 8) {
            float xq[4][8];
            #pragma unroll
            for (int r = 0; r < 4; ++r) {
                *reinterpret_cast<float4*>(&xq[r][0]) =
                    *reinterpret_cast<const float4*>(&xs[rbase + r][k0]);
                *reinterpret_cast<float4*>(&xq[r][4]) =
                    *reinterpret_cast<const float4*>(&xs[rbase + r][k0 + 4]);
            }
            #pragma unroll
            for (int kk = 0; kk < 8; ++kk) {
                const float w1 = pw1[kk * HH];
                const float wg = pwg[kk * HH];
                #pragma unroll
                for (int r = 0; r < 4; ++r) {
                    a1[r] = fmaf(xq[r][kk], w1, a1[r]);
                    ga[r] = fmaf(xq[r][kk], wg, ga[r]);
                }
            }
            pw1 += 8 * HH;
            pwg += 8 * HH;
        }
        float bb1 = b1[c], bbg = bg1[c];
        #pragma unroll
        for (int r = 0; r < 4; ++r) {
            float v1 = __fadd_rn(a1[r], bb1);
            float vg = __fadd_rn(ga[r], bbg);
            h1s[rbase + r][c] = v1 > 0.f ? v1 : 0.f;
            g1s[rbase + r][c] = vg > 0.f ? vg : 0.f;
        }
    }
    __syncthreads();

    // ---------- Phase 2: h2 = relu(h1@W2+b2), into cs-overlay ----------
    {
        const int c = tid & (HH - 1);
        const int rbase = (tid >> 7) * 4;
        const float* __restrict__ pw = W2 + c;
        float acc[4] = {0.f, 0.f, 0.f, 0.f};
        for (int k0 = 0; k0 < HH; k0 += 8) {
            float hq[4][8];
            #pragma unroll
            for (int r = 0; r < 4; ++r) {
                *reinterpret_cast<float4*>(&hq[r][0]) =
                    *reinterpret_cast<const float4*>(&h1s[rbase + r][k0]);
                *reinterpret_cast<float4*>(&hq[r][4]) =
                    *reinterpret_cast<const float4*>(&h1s[rbase + r][k0 + 4]);
            }
            #pragma unroll
            for (int kk = 0; kk < 8; ++kk) {
                const float w = pw[kk * HH];
                #pragma unroll
                for (int r = 0; r < 4; ++r)
                    acc[r] = fmaf(hq[r][kk], w, acc[r]);
            }
            pw += 8 * HH;
        }
        float bb = b2[c];
        #pragma unroll
        for (int r = 0; r < 4; ++r) {
            float v = __fadd_rn(acc[r], bb);
            h2f[(rbase + r) * HH + c] = v > 0.f ? v : 0.f;
        }
    }
    __syncthreads();

    // ---------- Phase 3: cs = sig(h2@W3+b3) * sig(g1@Wg2+bg2) ----------
    // Two separate k-loops (register peak control). Activation reads as
    // float4 quads; weights via one pointer + imm offsets {0,1024,2048,3072}.
    {
        const int c0 = tid, c1 = tid + NT;
        float zi0[TR], zi1[TR], zg0[TR], zg1[TR];
        #pragma unroll
        for (int r = 0; r < TR; ++r) { zi0[r] = 0.f; zi1[r] = 0.f; zg0[r] = 0.f; zg1[r] = 0.f; }
        {
            const float* __restrict__ pw = W3 + c0;
            for (int k0 = 0; k0 < HH; k0 += 4) {
                float hq[TR][4];
                #pragma unroll
                for (int r = 0; r < TR; ++r)
                    *reinterpret_cast<float4*>(&hq[r][0]) =
                        *reinterpret_cast<const float4*>(&h2f[r * HH + k0]);
                #pragma unroll
                for (int kk = 0; kk < 4; ++kk) {
                    const float w0 = pw[kk * BD];
                    const float w1 = pw[kk * BD + NT];
                    #pragma unroll
                    for (int r = 0; r < TR; ++r) {
                        zi0[r] = fmaf(hq[r][kk], w0, zi0[r]);
                        zi1[r] = fmaf(hq[r][kk], w1, zi1[r]);
                    }
                }
                pw += 4 * BD;
            }
        }
        {
            const float* __restrict__ pw = Wg2 + c0;
            for (int k0 = 0; k0 < HH; k0 += 4) {
                float gq[TR][4];
                #pragma unroll
                for (int r = 0; r < TR; ++r)
                    *reinterpret_cast<float4*>(&gq[r][0]) =
                        *reinterpret_cast<const float4*>(&g1s[r][k0]);
                #pragma unroll
                for (int kk = 0; kk < 4; ++kk) {
                    const float w0 = pw[kk * BD];
                    const float w1 = pw[kk * BD + NT];
                    #pragma unroll
                    for (int r = 0; r < TR; ++r) {
                        zg0[r] = fmaf(gq[r][kk], w0, zg0[r]);
                        zg1[r] = fmaf(gq[r][kk], w1, zg1[r]);
                    }
                }
                pw += 4 * BD;
            }
        }
        __syncthreads();   // all h2 reads complete before cs is overwritten
        float bi0 = b3[c0], bi1 = b3[c1];
        float bq0 = bg2[c0], bq1 = bg2[c1];
        #pragma unroll
        for (int r = 0; r < TR; ++r) {
            cs[r][c0] = __fmul_rn(sig_xla(__fadd_rn(zi0[r], bi0)),
                                  sig_xla(__fadd_rn(zg0[r], bq0)));
            cs[r][c1] = __fmul_rn(sig_xla(__fadd_rn(zi1[r], bi1)),
                                  sig_xla(__fadd_rn(zg1[r], bq1)));
        }
    }
    __syncthreads();

    // ---------- Phase 4: per-row top-K, exact on fp32 keys (FROZEN) ----------
    {
        const int lane = tid & 63;
        const int wv = tid >> 6;
        for (int rr = 0; rr < 2; ++rr) {
            const int r = wv + rr * 4;
            unsigned u[8];
            #pragma unroll
            for (int j = 0; j < 8; ++j)
                u[j] = __float_as_uint(cs[r][j * 64 + lane]);

            unsigned lo = 0u, hi = 0xffffffffu;
            while (lo < hi) {
                unsigned mid = lo + ((hi - lo) >> 1);
                int cnt = 0;
                #pragma unroll
                for (int j = 0; j < 8; ++j) cnt += (u[j] > mid) ? 1 : 0;
                cnt = wave_sum64(cnt);
                if (cnt < KSEL) hi = mid; else lo = mid + 1;
            }
            const unsigned T = lo;

            int ngt = 0, neq = 0;
            #pragma unroll
            for (int j = 0; j < 8; ++j) {
                ngt += (u[j] > T) ? 1 : 0;
                neq += (u[j] == T) ? 1 : 0;
            }
            ngt = wave_sum64(ngt);
            neq = wave_sum64(neq);
            const int m = KSEL - ngt;

            unsigned selbits = 0;
            #pragma unroll
            for (int j = 0; j < 8; ++j)
                if (u[j] > T) selbits |= (1u << j);

            if (neq == m) {
                #pragma unroll
                for (int j = 0; j < 8; ++j)
                    if (u[j] == T) selbits |= (1u << j);
            } else {
                int cnt8[8];
                #pragma unroll
                for (int j = 0; j < 8; ++j) cnt8[j] = 0;
                for (int jj = 0; jj < BD; ++jj) {
                    unsigned uj = __float_as_uint(cs[r][jj]);
                    if (uj == T) {
                        #pragma unroll
                        for (int j = 0; j < 8; ++j)
                            cnt8[j] += (u[j] == T && jj < (j * 64 + lane)) ? 1 : 0;
                    }
                }
                #pragma unroll
                for (int j = 0; j < 8; ++j)
                    if (u[j] == T && (ngt + cnt8[j]) < KSEL)
                        selbits |= (1u << j);
            }

            #pragma unroll
            for (int j = 0; j < 8; ++j)
                if (!(selbits & (1u << j))) xs[r][j * 64 + lane] = 0.0f;
        }
    }
    __syncthreads();

    // ---------- Phase R1: r = relu(masked@Wr1 + br1), into rs(=h1s) ----------
    {
        const int c = tid & (HH - 1);
        const int rbase = (tid >> 7) * 4;
        const float* __restrict__ pw = Wr1 + c;
        float acc[4] = {0.f, 0.f, 0.f, 0.f};
        for (int k0 = 0; k0 < BD; k0 += 8) {
            float xq[4][8];
            #pragma unroll
            for (int r = 0; r < 4; ++r) {
                *reinterpret_cast<float4*>(&xq[r][0]) =
                    *reinterpret_cast<const float4*>(&xs[rbase + r][k0]);
                *reinterpret_cast<float4*>(&xq[r][4]) =
                    *reinterpret_cast<const float4*>(&xs[rbase + r][k0 + 4]);
            }
            #pragma unroll
            for (int kk = 0; kk < 8; ++kk) {
                const float w = pw[kk * HH];
                #pragma unroll
                for (int r = 0; r < 4; ++r)
                    acc[r] = fmaf(xq[r][kk], w, acc[r]);
            }
            pw += 8 * HH;
        }
        float bb = br1[c];
        #pragma unroll
        for (int r = 0; r < 4; ++r) {
            float v = acc[r] + bb;
            rs[rbase + r][c] = v > 0.f ? v : 0.f;
        }
    }
    __syncthreads();

    // ---------- Phase R2: out = r@Wr2 + br2 ----------
    {
        for (int cc = tid; cc < KSEL; cc += NT) {
            const float* __restrict__ pw = Wr2 + cc;
            float acc[TR];
            #pragma unroll
            for (int r = 0; r < TR; ++r) acc[r] = 0.f;
            for (int k0 = 0; k0 < HH; k0 += 4) {
                float rq[TR][4];
                #pragma unroll
                for (int r = 0; r < TR; ++r)
                    *reinterpret_cast<float4*>(&rq[r][0]) =
                        *reinterpret_cast<const float4*>(&rs[r][k0]);
                #pragma unroll
                for (int kk = 0; kk < 4; ++kk) {
                    const float w = pw[kk * KSEL];
                    #pragma unroll
                    for (int r = 0; r < TR; ++r)
                        acc[r] = fmaf(rq[r][kk], w, acc[r]);
                }
                pw += 4 * KSEL;
            }
            float bb = br2[cc];
            #pragma unroll
            for (int r = 0; r < TR; ++r)
                out[(row0 + r) * KSEL + cc] = acc[r] + bb;
        }
    }
}

extern "C" void kernel_launch(void* const* d_in, const int* in_sizes, int n_in,
                              void* d_out, int out_size, void* d_ws, size_t ws_size,
                              hipStream_t stream) {
    const float* x   = (const float*)d_in[0];
    const float* W1  = (const float*)d_in[1];
    const float* b1  = (const float*)d_in[2];
    const float* W2  = (const float*)d_in[3];
    const float* b2  = (const float*)d_in[4];
    const float* W3  = (const float*)d_in[5];
    const float* b3  = (const float*)d_in[6];
    const float* Wg1 = (const float*)d_in[7];
    const float* bg1 = (const float*)d_in[8];
    const float* Wg2 = (const float*)d_in[9];
    const float* bg2 = (const float*)d_in[10];
    const float* Wr1 = (const float*)d_in[11];
    const float* br1 = (const float*)d_in[12];
    const float* Wr2 = (const float*)d_in[13];
    const float* br2 = (const float*)d_in[14];
    float* out = (float*)d_out;

    const int nrows = in_sizes[0] / BD;          // 65536
    dim3 grid(nrows / TR), block(NT);
    afs_fused<<<grid, block, 0, stream>>>(x, W1, b1, W2, b2, W3, b3,
                                          Wg1, bg1, Wg2, bg2, Wr1, br1, Wr2, br2, out);
}